// Round 1
// baseline (376.530 us; speedup 1.0000x reference)
//
#include <hip/hip_runtime.h>
#include <math.h>

// Problem constants (from reference): B=64, S=4096, H=256.
namespace {
constexpr int kB = 64;
constexpr int kS = 4096;
constexpr int kH = 256;
constexpr int kChunks = 32;                       // chunks per batch row
constexpr int kChunkS = kS / kChunks;             // 128 positions per block
constexpr int kWavesPerBlock = 4;                 // 256 threads
constexpr int kPosPerWave = kChunkS / kWavesPerBlock; // 32 positions per wave
constexpr int kPartStride = kH + 2;               // acc[256] + m + l
constexpr float kNeg = 1e30f;
}

// Pass 1: flash-style online softmax-weighted sum over a chunk of S.
// One wave per 32 positions; 64 lanes x float4 = one 1KiB coalesced row.
__global__ __launch_bounds__(256, 8) void pass1_kernel(
    const float* __restrict__ x, const float* __restrict__ mask,
    const float* __restrict__ q, float* __restrict__ part) {
  const int blk = blockIdx.x;
  const int b = blk >> 5;           // blk / kChunks
  const int c = blk & (kChunks - 1);
  const int tid = threadIdx.x;
  const int wave = tid >> 6;
  const int lane = tid & 63;

  const float4 q4 = *reinterpret_cast<const float4*>(q + b * kH + lane * 4);
  const float* xb = x + (size_t)b * kS * kH;
  const float* mrow = mask + b * kS;
  const int s_base = c * kChunkS + wave * kPosPerWave;

  float m = -INFINITY;
  float l = 0.f;
  float4 acc = make_float4(0.f, 0.f, 0.f, 0.f);

  #pragma unroll 4
  for (int i = 0; i < kPosPerWave; ++i) {
    const int s = s_base + i;
    const float4 x4 =
        *reinterpret_cast<const float4*>(xb + (size_t)s * kH + lane * 4);
    float p = x4.x * q4.x + x4.y * q4.y + x4.z * q4.z + x4.w * q4.w;
    #pragma unroll
    for (int off = 32; off > 0; off >>= 1) p += __shfl_xor(p, off, 64);
    const float score = p - kNeg * (1.0f - mrow[s]);  // masked -> ~ -1e30 (finite)
    const float m_new = fmaxf(m, score);
    const float alpha = __expf(m - m_new);            // exp(-inf)=0, no NaN path
    const float w = __expf(score - m_new);
    l = l * alpha + w;
    acc.x = acc.x * alpha + w * x4.x;
    acc.y = acc.y * alpha + w * x4.y;
    acc.z = acc.z * alpha + w * x4.z;
    acc.w = acc.w * alpha + w * x4.w;
    m = m_new;
  }

  // Combine the block's 4 waves in LDS.
  __shared__ float sm[kWavesPerBlock];
  __shared__ float sl[kWavesPerBlock];
  __shared__ float sacc[kWavesPerBlock][kH];
  if (lane == 0) { sm[wave] = m; sl[wave] = l; }
  *reinterpret_cast<float4*>(&sacc[wave][lane * 4]) = acc;
  __syncthreads();

  const float m_b = fmaxf(fmaxf(sm[0], sm[1]), fmaxf(sm[2], sm[3]));
  const float a0 = __expf(sm[0] - m_b);
  const float a1 = __expf(sm[1] - m_b);
  const float a2 = __expf(sm[2] - m_b);
  const float a3 = __expf(sm[3] - m_b);
  float* out = part + (size_t)blk * kPartStride;
  out[tid] = sacc[0][tid] * a0 + sacc[1][tid] * a1 +
             sacc[2][tid] * a2 + sacc[3][tid] * a3;
  if (tid == 0) {
    out[kH] = m_b;
    out[kH + 1] = sl[0] * a0 + sl[1] * a1 + sl[2] * a2 + sl[3] * a3;
  }
}

// Pass 2: per-batch combine of 32 partials + fused 512->256 linear epilogue.
__global__ __launch_bounds__(256, 4) void pass2_kernel(
    const float* __restrict__ part, const float* __restrict__ q,
    const float* __restrict__ W, const float* __restrict__ bias,
    float* __restrict__ out) {
  const int b = blockIdx.x;
  const int tid = threadIdx.x;

  const float* pb = part + (size_t)b * kChunks * kPartStride;
  float m_g = -INFINITY;
  #pragma unroll
  for (int c = 0; c < kChunks; ++c)
    m_g = fmaxf(m_g, pb[c * kPartStride + kH]);
  float l_g = 0.f, num = 0.f;
  #pragma unroll 4
  for (int c = 0; c < kChunks; ++c) {
    const float* p = pb + c * kPartStride;
    const float scale = __expf(p[kH] - m_g);
    l_g += scale * p[kH + 1];
    num += scale * p[tid];          // coalesced across the 256 threads
  }
  const float msg = num / l_g;
  out[(size_t)b * kH + tid] = msg;  // output 0: extracted_msg

  __shared__ float conc[2 * kH];
  conc[tid] = q[b * kH + tid];
  conc[kH + tid] = msg;
  __syncthreads();

  float acc = bias[tid];
  const float* wr = W + (size_t)tid * (2 * kH);   // row h = tid of W [H, 2H]
  #pragma unroll 8
  for (int j = 0; j < 2 * kH; j += 4) {
    const float4 w4 = *reinterpret_cast<const float4*>(wr + j);
    acc += conc[j] * w4.x + conc[j + 1] * w4.y +
           conc[j + 2] * w4.z + conc[j + 3] * w4.w;
  }
  out[(size_t)(kB * kH) + (size_t)b * kH + tid] = acc;  // output 1: control_emb
}

extern "C" void kernel_launch(void* const* d_in, const int* in_sizes, int n_in,
                              void* d_out, int out_size, void* d_ws, size_t ws_size,
                              hipStream_t stream) {
  const float* x    = (const float*)d_in[0];  // inp_seq [B,S,H]
  const float* mask = (const float*)d_in[1];  // [B,S]
  const float* q    = (const float*)d_in[2];  // [B,H]
  const float* W    = (const float*)d_in[3];  // [H,2H]
  const float* bias = (const float*)d_in[4];  // [H]
  float* out = (float*)d_out;                 // [B*H extracted_msg][B*H control_emb]
  float* part = (float*)d_ws;                 // B*kChunks*(H+2) floats = 2.1 MB

  pass1_kernel<<<kB * kChunks, 256, 0, stream>>>(x, mask, q, part);
  pass2_kernel<<<kB, 256, 0, stream>>>(part, q, W, bias, out);
}